// Round 1
// baseline (4623.183 us; speedup 1.0000x reference)
//
#include <hip/hip_runtime.h>

#define N_TOT 32768   // 32*1024 rows
#define DDIM  512
#define KCB   8192

// ---------------- Kernel A: codebook squared norms (one wave per row) ----------------
__global__ void cnorm_kernel(const float* __restrict__ cb, float* __restrict__ cnorm) {
    int wave = (blockIdx.x * blockDim.x + threadIdx.x) >> 6;
    int lane = threadIdx.x & 63;
    if (wave >= KCB) return;
    const float* row = cb + (size_t)wave * DDIM;
    float s = 0.f;
#pragma unroll
    for (int j = 0; j < DDIM / 64; ++j) {
        float v = row[lane + 64 * j];
        s += v * v;
    }
#pragma unroll
    for (int off = 32; off > 0; off >>= 1) s += __shfl_down(s, off, 64);
    if (lane == 0) cnorm[wave] = s;
}

// ---------------- Kernel B: fused fp32 GEMM + per-row argmin ----------------
// score[n,k] = cnorm[k] - 2 * dot(x_n, c_k)   (||x||^2 dropped: constant per row)
#define BN 64
#define BK 64
#define BD 32
#define LDA (BN + 4)   // +4 keeps 16B alignment for float4 LDS reads, breaks pow2 stride

__global__ __launch_bounds__(256) void argmin_kernel(
    const float* __restrict__ x, const float* __restrict__ cb,
    const float* __restrict__ cnorm, int* __restrict__ indices) {
    __shared__ float As[BD][LDA];   // transposed: As[d][row]
    __shared__ float Bs[BD][LDA];   // transposed: Bs[d][col]
    __shared__ float redv[BN][16];
    __shared__ int   redi[BN][16];

    const int tid = threadIdx.x;
    const int tx = tid & 15;   // col group (4 cols each)
    const int ty = tid >> 4;   // row group (4 rows each)
    const int row0 = blockIdx.x * BN;

    float best[4];
    int   bidx[4];
#pragma unroll
    for (int i = 0; i < 4; ++i) { best[i] = 3.402823466e+38f; bidx[i] = KCB; }

    for (int k0 = 0; k0 < KCB; k0 += BK) {
        float acc[4][4] = {};
        for (int d0 = 0; d0 < DDIM; d0 += BD) {
            // Stage 64x32 chunks of x rows and codebook rows, transposed, into LDS.
            // 512 float4 quads per matrix; 256 threads -> 2 each.
#pragma unroll
            for (int t = 0; t < 2; ++t) {
                int q  = tid + t * 256;
                int r  = q >> 3;       // tile row 0..63
                int dq = q & 7;        // which float4 along depth
                float4 v = *(const float4*)(x  + (size_t)(row0 + r) * DDIM + d0 + dq * 4);
                As[dq * 4 + 0][r] = v.x; As[dq * 4 + 1][r] = v.y;
                As[dq * 4 + 2][r] = v.z; As[dq * 4 + 3][r] = v.w;
                float4 w = *(const float4*)(cb + (size_t)(k0 + r) * DDIM + d0 + dq * 4);
                Bs[dq * 4 + 0][r] = w.x; Bs[dq * 4 + 1][r] = w.y;
                Bs[dq * 4 + 2][r] = w.z; Bs[dq * 4 + 3][r] = w.w;
            }
            __syncthreads();
#pragma unroll
            for (int d = 0; d < BD; ++d) {
                float4 av = *(const float4*)&As[d][ty * 4];
                float4 bv = *(const float4*)&Bs[d][tx * 4];
                float a[4] = {av.x, av.y, av.z, av.w};
                float b[4] = {bv.x, bv.y, bv.z, bv.w};
#pragma unroll
                for (int i = 0; i < 4; ++i)
#pragma unroll
                    for (int j = 0; j < 4; ++j)
                        acc[i][j] += a[i] * b[j];
            }
            __syncthreads();
        }
        // fold this k-tile into running argmin
#pragma unroll
        for (int j = 0; j < 4; ++j) {
            int k = k0 + tx * 4 + j;
            float cn = cnorm[k];
#pragma unroll
            for (int i = 0; i < 4; ++i) {
                float s = cn - 2.0f * acc[i][j];
                if (s < best[i] || (s == best[i] && k < bidx[i])) { best[i] = s; bidx[i] = k; }
            }
        }
    }
    // cross-thread reduce: 16 tx-threads share each row
#pragma unroll
    for (int i = 0; i < 4; ++i) { redv[ty * 4 + i][tx] = best[i]; redi[ty * 4 + i][tx] = bidx[i]; }
    __syncthreads();
    if (tid < BN) {
        float bv = redv[tid][0]; int bi = redi[tid][0];
#pragma unroll
        for (int t = 1; t < 16; ++t) {
            float v = redv[tid][t]; int ii = redi[tid][t];
            if (v < bv || (v == bv && ii < bi)) { bv = v; bi = ii; }
        }
        indices[row0 + tid] = bi;
    }
}

// ---------------- Kernel C: gather + straight-through output + loss partials ----------------
__global__ __launch_bounds__(256) void output_kernel(
    const float* __restrict__ x, const float* __restrict__ cb,
    const int* __restrict__ indices, float* __restrict__ out,
    float* __restrict__ loss_acc) {
    size_t base = ((size_t)blockIdx.x * blockDim.x + threadIdx.x) * 16;
    int n = (int)(base >> 9);       // 16 consecutive elements never cross a row (512 % 16 == 0)
    int d = (int)(base & 511);
    int idx = indices[n];
    const float* cr = cb + (size_t)idx * DDIM + d;
    const float* xr = x + base;
    float* orow = out + base;
    float lsum = 0.f;
#pragma unroll
    for (int t = 0; t < 4; ++t) {
        float4 q  = *(const float4*)(cr + t * 4);
        float4 xv = *(const float4*)(xr + t * 4);
        float dx0 = q.x - xv.x, dx1 = q.y - xv.y, dx2 = q.z - xv.z, dx3 = q.w - xv.w;
        float4 o;
        o.x = xv.x + dx0; o.y = xv.y + dx1; o.z = xv.z + dx2; o.w = xv.w + dx3;
        *(float4*)(orow + t * 4) = o;
        lsum += dx0 * dx0 + dx1 * dx1 + dx2 * dx2 + dx3 * dx3;
    }
#pragma unroll
    for (int off = 32; off > 0; off >>= 1) lsum += __shfl_down(lsum, off, 64);
    __shared__ float wsum[4];
    int lane = threadIdx.x & 63, wv = threadIdx.x >> 6;
    if (lane == 0) wsum[wv] = lsum;
    __syncthreads();
    if (threadIdx.x == 0) atomicAdd(loss_acc, wsum[0] + wsum[1] + wsum[2] + wsum[3]);
}

// ---------------- Kernel D: finalize loss ----------------
__global__ void finalize_kernel(const float* __restrict__ loss_acc, float* __restrict__ out_loss) {
    *out_loss = (*loss_acc) * (0.25f / (float)((size_t)N_TOT * DDIM));
}

extern "C" void kernel_launch(void* const* d_in, const int* in_sizes, int n_in,
                              void* d_out, int out_size, void* d_ws, size_t ws_size,
                              hipStream_t stream) {
    const float* x  = (const float*)d_in[0];
    const float* cb = (const float*)d_in[1];
    float* out = (float*)d_out;

    char* ws = (char*)d_ws;
    float* loss_acc = (float*)ws;                          // 4 B
    int*   indices  = (int*)(ws + 256);                    // 128 KiB
    float* cnorm    = (float*)(ws + 256 + 4 * N_TOT);      // 32 KiB

    hipMemsetAsync(loss_acc, 0, 4, stream);
    cnorm_kernel<<<KCB / 4, 256, 0, stream>>>(cb, cnorm);
    argmin_kernel<<<N_TOT / BN, 256, 0, stream>>>(x, cb, cnorm, indices);
    output_kernel<<<((size_t)N_TOT * DDIM) / (256 * 16), 256, 0, stream>>>(
        x, cb, indices, out, loss_acc);
    finalize_kernel<<<1, 1, 0, stream>>>(loss_acc, out + (size_t)N_TOT * DDIM);
}

// Round 2
// 3722.757 us; speedup vs baseline: 1.2419x; 1.2419x over previous
//
#include <hip/hip_runtime.h>
#include <stdint.h>

#define N_TOT 32768
#define DDIM  512
#define KCB   8192
#define NSPLIT 4
#define COLS_SPLIT (KCB / NSPLIT)   // 2048
#define BN 128
#define BC 128
#define BKD 64                      // d-chunk depth in halfs
#define NTILES (COLS_SPLIT / BC)    // 16
#define MARGIN 0.15f

typedef _Float16 half8 __attribute__((ext_vector_type(8)));
typedef float    floatx4 __attribute__((ext_vector_type(4)));

// ---------------- async global->LDS 16B ----------------
typedef const __attribute__((address_space(1))) unsigned int* gas_ptr;
typedef __attribute__((address_space(3))) unsigned int* las_ptr;
__device__ __forceinline__ void gld_lds16(void* l, const void* g) {
    __builtin_amdgcn_global_load_lds((gas_ptr)g, (las_ptr)l, 16, 0, 0);
}

// ---------------- convert x to fp16 ----------------
__global__ __launch_bounds__(256) void convert_x_kernel(
    const float* __restrict__ x, _Float16* __restrict__ xh) {
    size_t i = ((size_t)blockIdx.x * 256 + threadIdx.x) * 8;
    float4 v0 = *(const float4*)(x + i);
    float4 v1 = *(const float4*)(x + i + 4);
    half8 h;
    h[0] = (_Float16)v0.x; h[1] = (_Float16)v0.y; h[2] = (_Float16)v0.z; h[3] = (_Float16)v0.w;
    h[4] = (_Float16)v1.x; h[5] = (_Float16)v1.y; h[6] = (_Float16)v1.z; h[7] = (_Float16)v1.w;
    *(half8*)(xh + i) = h;
}

// ---------------- convert codebook to fp16 + fp32 norms (one wave/row) ----------------
__global__ __launch_bounds__(256) void convert_cb_kernel(
    const float* __restrict__ cb, _Float16* __restrict__ cbh, float* __restrict__ cnorm) {
    int row = blockIdx.x * 4 + (threadIdx.x >> 6);
    int lane = threadIdx.x & 63;
    const float* src = cb + (size_t)row * DDIM + lane * 8;
    float4 v0 = *(const float4*)src;
    float4 v1 = *(const float4*)(src + 4);
    half8 h;
    h[0] = (_Float16)v0.x; h[1] = (_Float16)v0.y; h[2] = (_Float16)v0.z; h[3] = (_Float16)v0.w;
    h[4] = (_Float16)v1.x; h[5] = (_Float16)v1.y; h[6] = (_Float16)v1.z; h[7] = (_Float16)v1.w;
    *(half8*)(cbh + (size_t)row * DDIM + lane * 8) = h;
    float s = v0.x*v0.x + v0.y*v0.y + v0.z*v0.z + v0.w*v0.w
            + v1.x*v1.x + v1.y*v1.y + v1.z*v1.z + v1.w*v1.w;
#pragma unroll
    for (int off = 32; off > 0; off >>= 1) s += __shfl_down(s, off, 64);
    if (lane == 0) cnorm[row] = s;
}

// ---------------- fused fp16 MFMA GEMM + per-row top-2 argmin (K-split) ----------------
__global__ __launch_bounds__(256, 2) void gemm_argmin_kernel(
    const _Float16* __restrict__ xh, const _Float16* __restrict__ cbh,
    const float* __restrict__ cnorm,
    float* __restrict__ sb1, int* __restrict__ si1, float* __restrict__ sb2) {

    __shared__ __align__(16) _Float16 smem[16384];  // As[128][64] + Bs[128][64], chunk-swizzled
    _Float16* As = smem;
    _Float16* Bs = smem + 8192;

    const int tid = threadIdx.x;
    const int wave = tid >> 6;
    const int lane = tid & 63;
    const int rowHalf = wave >> 1;
    const int colHalf = wave & 1;
    const int l15 = lane & 15;
    const int quad = lane >> 4;

    const int row0 = blockIdx.x * BN;
    const int colBase = blockIdx.y * COLS_SPLIT;

    float b1[16], b2[16];
    int   i1[16];
#pragma unroll
    for (int s = 0; s < 16; ++s) { b1[s] = 3.402823466e38f; b2[s] = 3.402823466e38f; i1[s] = 0; }

    for (int tile = 0; tile < NTILES; ++tile) {
        const int col0 = colBase + tile * BC;
        floatx4 acc[4][4];
#pragma unroll
        for (int i = 0; i < 4; ++i)
#pragma unroll
            for (int j = 0; j < 4; ++j)
                acc[i][j] = (floatx4){0.f, 0.f, 0.f, 0.f};

        for (int d0 = 0; d0 < DDIM; d0 += BKD) {
            __syncthreads();   // previous chunk's LDS reads done before overwrite
            // stage A tile: 1024 16B chunks; wave w covers chunks [w*256, w*256+256)
#pragma unroll
            for (int r = 0; r < 4; ++r) {
                int c = wave * 256 + r * 64 + lane;
                int ar = c >> 3;
                int q  = (c & 7) ^ (ar & 7);      // XOR swizzle: conflict-free frag reads
                gld_lds16(As + (wave * 256 + r * 64) * 8,
                          xh + (((size_t)(row0 + ar)) << 9) + d0 + q * 8);
            }
#pragma unroll
            for (int r = 0; r < 4; ++r) {
                int c = wave * 256 + r * 64 + lane;
                int br = c >> 3;
                int q  = (c & 7) ^ (br & 7);
                gld_lds16(Bs + (wave * 256 + r * 64) * 8,
                          cbh + (((size_t)(col0 + br)) << 9) + d0 + q * 8);
            }
            __syncthreads();   // loads visible
#pragma unroll
            for (int kh = 0; kh < 2; ++kh) {
                half8 af[4], bf[4];
#pragma unroll
                for (int i = 0; i < 4; ++i) {
                    int rr = rowHalf * 64 + i * 16 + l15;
                    int qs = (kh * 4 + quad) ^ (rr & 7);
                    af[i] = *(const half8*)(As + rr * 64 + qs * 8);
                }
#pragma unroll
                for (int j = 0; j < 4; ++j) {
                    int cc = colHalf * 64 + j * 16 + l15;
                    int qs = (kh * 4 + quad) ^ (cc & 7);
                    bf[j] = *(const half8*)(Bs + cc * 64 + qs * 8);
                }
#pragma unroll
                for (int i = 0; i < 4; ++i)
#pragma unroll
                    for (int j = 0; j < 4; ++j)
                        acc[i][j] = __builtin_amdgcn_mfma_f32_16x16x32_f16(
                            af[i], bf[j], acc[i][j], 0, 0, 0);
            }
        }
        // epilogue: fold scores into per-lane top-2
#pragma unroll
        for (int j = 0; j < 4; ++j) {
            int col = col0 + colHalf * 64 + j * 16 + l15;
            float cn = cnorm[col];
#pragma unroll
            for (int i = 0; i < 4; ++i) {
#pragma unroll
                for (int r = 0; r < 4; ++r) {
                    float s = fmaf(-2.0f, acc[i][j][r], cn);
                    int slot = i * 4 + r;
                    if (s < b1[slot]) { b2[slot] = b1[slot]; b1[slot] = s; i1[slot] = col; }
                    else if (s < b2[slot]) b2[slot] = s;
                }
            }
        }
    }

    // butterfly merge across the 16 col-lanes sharing each row
#pragma unroll
    for (int m = 1; m < 16; m <<= 1) {
#pragma unroll
        for (int s = 0; s < 16; ++s) {
            float ob1 = __shfl_xor(b1[s], m, 64);
            float ob2 = __shfl_xor(b2[s], m, 64);
            int   oi1 = __shfl_xor(i1[s], m, 64);
            if (ob1 < b1[s] || (ob1 == b1[s] && oi1 < i1[s])) {
                b2[s] = fminf(b1[s], ob2);
                b1[s] = ob1; i1[s] = oi1;
            } else {
                b2[s] = fminf(b2[s], ob1);
            }
        }
    }

    __syncthreads();   // done with As/Bs; reuse smem for cross-wave merge
    float* mb1 = (float*)smem;           // [2 colHalf][128 rows]
    float* mb2 = mb1 + 256;
    int*   mi1 = (int*)(mb2 + 256);
    if (l15 == 0) {
#pragma unroll
        for (int s = 0; s < 16; ++s) {
            int row = rowHalf * 64 + (s >> 2) * 16 + quad * 4 + (s & 3);
            mb1[colHalf * 128 + row] = b1[s];
            mb2[colHalf * 128 + row] = b2[s];
            mi1[colHalf * 128 + row] = i1[s];
        }
    }
    __syncthreads();
    if (tid < 128) {
        float a1 = mb1[tid], a2 = mb2[tid]; int ai = mi1[tid];
        float c1 = mb1[128 + tid], c2 = mb2[128 + tid]; int ci = mi1[128 + tid];
        float r1, r2; int ri;
        if (c1 < a1 || (c1 == a1 && ci < ai)) { r1 = c1; ri = ci; r2 = fminf(a1, c2); }
        else { r1 = a1; ri = ai; r2 = fminf(a2, c1); }
        size_t o = (size_t)blockIdx.y * N_TOT + row0 + tid;
        sb1[o] = r1; si1[o] = ri; sb2[o] = r2;
    }
}

// ---------------- merge K-splits, emit index + near-tie flag ----------------
__global__ __launch_bounds__(256) void merge_kernel(
    const float* __restrict__ sb1, const int* __restrict__ si1, const float* __restrict__ sb2,
    int* __restrict__ indices, int* __restrict__ flags) {
    int n = blockIdx.x * 256 + threadIdx.x;
    float b1 = sb1[n]; int i1 = si1[n]; float b2 = sb2[n];
#pragma unroll
    for (int s = 1; s < NSPLIT; ++s) {
        float ob1 = sb1[(size_t)s * N_TOT + n];
        int   oi1 = si1[(size_t)s * N_TOT + n];
        float ob2 = sb2[(size_t)s * N_TOT + n];
        if (ob1 < b1 || (ob1 == b1 && oi1 < i1)) { b2 = fminf(b1, ob2); b1 = ob1; i1 = oi1; }
        else b2 = fminf(b2, ob1);
    }
    indices[n] = i1;
    flags[n] = (b2 - b1 < MARGIN) ? 1 : 0;
}

// ---------------- exact fp32 rescan for near-tie rows ----------------
__global__ __launch_bounds__(256) void repair_kernel(
    const float* __restrict__ x, const float* __restrict__ cb,
    const float* __restrict__ cnorm, const int* __restrict__ flags,
    int* __restrict__ indices) {
    __shared__ float xrow[512];
    __shared__ float rbest[256];
    __shared__ int   ridx[256];
    for (int r = 0; r < 128; ++r) {
        int n = blockIdx.x * 128 + r;
        if (flags[n] == 0) continue;   // uniform branch
        __syncthreads();
        for (int t = threadIdx.x; t < 512; t += 256) xrow[t] = x[(size_t)n * 512 + t];
        __syncthreads();
        float best = 3.402823466e38f; int bidx = 0;
        for (int k = threadIdx.x; k < KCB; k += 256) {
            const float* crow = cb + (size_t)k * 512;
            float d0 = 0.f, d1 = 0.f, d2 = 0.f, d3 = 0.f;
            for (int t = 0; t < 512; t += 16) {
                float4 c0 = *(const float4*)(crow + t);
                float4 c1 = *(const float4*)(crow + t + 4);
                float4 c2 = *(const float4*)(crow + t + 8);
                float4 c3 = *(const float4*)(crow + t + 12);
                d0 = fmaf(c0.x, xrow[t+0], d0);  d0 = fmaf(c0.y, xrow[t+1], d0);
                d0 = fmaf(c0.z, xrow[t+2], d0);  d0 = fmaf(c0.w, xrow[t+3], d0);
                d1 = fmaf(c1.x, xrow[t+4], d1);  d1 = fmaf(c1.y, xrow[t+5], d1);
                d1 = fmaf(c1.z, xrow[t+6], d1);  d1 = fmaf(c1.w, xrow[t+7], d1);
                d2 = fmaf(c2.x, xrow[t+8], d2);  d2 = fmaf(c2.y, xrow[t+9], d2);
                d2 = fmaf(c2.z, xrow[t+10], d2); d2 = fmaf(c2.w, xrow[t+11], d2);
                d3 = fmaf(c3.x, xrow[t+12], d3); d3 = fmaf(c3.y, xrow[t+13], d3);
                d3 = fmaf(c3.z, xrow[t+14], d3); d3 = fmaf(c3.w, xrow[t+15], d3);
            }
            float s = cnorm[k] - 2.f * ((d0 + d1) + (d2 + d3));
            if (s < best) { best = s; bidx = k; }
        }
        rbest[threadIdx.x] = best; ridx[threadIdx.x] = bidx;
        __syncthreads();
        if (threadIdx.x == 0) {
            float bb = rbest[0]; int bi = ridx[0];
            for (int t = 1; t < 256; ++t)
                if (rbest[t] < bb || (rbest[t] == bb && ridx[t] < bi)) { bb = rbest[t]; bi = ridx[t]; }
            indices[n] = bi;
        }
        __syncthreads();
    }
}

// ---------------- fallback fp32 argmin (round-1), used only if ws too small ----------------
__global__ void cnorm_kernel(const float* __restrict__ cb, float* __restrict__ cnorm) {
    int wave = (blockIdx.x * blockDim.x + threadIdx.x) >> 6;
    int lane = threadIdx.x & 63;
    if (wave >= KCB) return;
    const float* row = cb + (size_t)wave * DDIM;
    float s = 0.f;
#pragma unroll
    for (int j = 0; j < DDIM / 64; ++j) { float v = row[lane + 64 * j]; s += v * v; }
#pragma unroll
    for (int off = 32; off > 0; off >>= 1) s += __shfl_down(s, off, 64);
    if (lane == 0) cnorm[wave] = s;
}

#define FBN 64
#define FBD 32
#define FLDA (FBN + 4)
__global__ __launch_bounds__(256) void argmin_fp32_kernel(
    const float* __restrict__ x, const float* __restrict__ cb,
    const float* __restrict__ cnorm, int* __restrict__ indices) {
    __shared__ float As[FBD][FLDA];
    __shared__ float Bs[FBD][FLDA];
    __shared__ float redv[FBN][16];
    __shared__ int   redi[FBN][16];
    const int tid = threadIdx.x;
    const int tx = tid & 15, ty = tid >> 4;
    const int row0 = blockIdx.x * FBN;
    float best[4]; int bidx[4];
#pragma unroll
    for (int i = 0; i < 4; ++i) { best[i] = 3.402823466e+38f; bidx[i] = KCB; }
    for (int k0 = 0; k0 < KCB; k0 += 64) {
        float acc[4][4] = {};
        for (int d0 = 0; d0 < DDIM; d0 += FBD) {
#pragma unroll
            for (int t = 0; t < 2; ++t) {
                int q = tid + t * 256, rr = q >> 3, dq = q & 7;
                float4 v = *(const float4*)(x + (size_t)(row0 + rr) * DDIM + d0 + dq * 4);
                As[dq*4+0][rr] = v.x; As[dq*4+1][rr] = v.y; As[dq*4+2][rr] = v.z; As[dq*4+3][rr] = v.w;
                float4 w = *(const float4*)(cb + (size_t)(k0 + rr) * DDIM + d0 + dq * 4);
                Bs[dq*4+0][rr] = w.x; Bs[dq*4+1][rr] = w.y; Bs[dq*4+2][rr] = w.z; Bs[dq*4+3][rr] = w.w;
            }
            __syncthreads();
#pragma unroll
            for (int d = 0; d < FBD; ++d) {
                float4 av = *(const float4*)&As[d][ty * 4];
                float4 bv = *(const float4*)&Bs[d][tx * 4];
                float a[4] = {av.x, av.y, av.z, av.w}, b[4] = {bv.x, bv.y, bv.z, bv.w};
#pragma unroll
                for (int i = 0; i < 4; ++i)
#pragma unroll
                    for (int j = 0; j < 4; ++j) acc[i][j] += a[i] * b[j];
            }
            __syncthreads();
        }
#pragma unroll
        for (int j = 0; j < 4; ++j) {
            int k = k0 + tx * 4 + j;
            float cn = cnorm[k];
#pragma unroll
            for (int i = 0; i < 4; ++i) {
                float s = cn - 2.0f * acc[i][j];
                if (s < best[i] || (s == best[i] && k < bidx[i])) { best[i] = s; bidx[i] = k; }
            }
        }
    }
#pragma unroll
    for (int i = 0; i < 4; ++i) { redv[ty*4+i][tx] = best[i]; redi[ty*4+i][tx] = bidx[i]; }
    __syncthreads();
    if (tid < FBN) {
        float bv = redv[tid][0]; int bi = redi[tid][0];
#pragma unroll
        for (int t = 1; t < 16; ++t) {
            float v = redv[tid][t]; int ii = redi[tid][t];
            if (v < bv || (v == bv && ii < bi)) { bv = v; bi = ii; }
        }
        indices[row0 + tid] = bi;
    }
}

// ---------------- gather + straight-through output + loss ----------------
__global__ __launch_bounds__(256) void output_kernel(
    const float* __restrict__ x, const float* __restrict__ cb,
    const int* __restrict__ indices, float* __restrict__ out,
    float* __restrict__ loss_acc) {
    size_t base = ((size_t)blockIdx.x * blockDim.x + threadIdx.x) * 16;
    int n = (int)(base >> 9);
    int d = (int)(base & 511);
    int idx = indices[n];
    const float* cr = cb + (size_t)idx * DDIM + d;
    const float* xr = x + base;
    float* orow = out + base;
    float lsum = 0.f;
#pragma unroll
    for (int t = 0; t < 4; ++t) {
        float4 q  = *(const float4*)(cr + t * 4);
        float4 xv = *(const float4*)(xr + t * 4);
        float dx0 = q.x - xv.x, dx1 = q.y - xv.y, dx2 = q.z - xv.z, dx3 = q.w - xv.w;
        float4 o;
        o.x = xv.x + dx0; o.y = xv.y + dx1; o.z = xv.z + dx2; o.w = xv.w + dx3;
        *(float4*)(orow + t * 4) = o;
        lsum += dx0*dx0 + dx1*dx1 + dx2*dx2 + dx3*dx3;
    }
#pragma unroll
    for (int off = 32; off > 0; off >>= 1) lsum += __shfl_down(lsum, off, 64);
    __shared__ float wsum[4];
    int lane = threadIdx.x & 63, wv = threadIdx.x >> 6;
    if (lane == 0) wsum[wv] = lsum;
    __syncthreads();
    if (threadIdx.x == 0) atomicAdd(loss_acc, wsum[0] + wsum[1] + wsum[2] + wsum[3]);
}

__global__ void finalize_kernel(const float* __restrict__ loss_acc, float* __restrict__ out_loss) {
    *out_loss = (*loss_acc) * (0.25f / (float)((size_t)N_TOT * DDIM));
}

extern "C" void kernel_launch(void* const* d_in, const int* in_sizes, int n_in,
                              void* d_out, int out_size, void* d_ws, size_t ws_size,
                              hipStream_t stream) {
    const float* x  = (const float*)d_in[0];
    const float* cb = (const float*)d_in[1];
    float* out = (float*)d_out;

    char* ws = (char*)d_ws;
    float* loss_acc = (float*)ws;                                 // 4 B
    int*   indices  = (int*)(ws + 256);                           // 128 KiB
    int*   flags    = (int*)(ws + 256 + 131072);                  // 128 KiB
    float* cnorm    = (float*)(ws + 256 + 2 * 131072);            // 32 KiB
    size_t off = 256 + 2 * 131072 + 32768;                        // 295168 (256-aligned)
    _Float16* xh  = (_Float16*)(ws + off);                        // 32 MiB
    _Float16* cbh = (_Float16*)(ws + off + (size_t)N_TOT * DDIM * 2);
    size_t soff = off + (size_t)N_TOT * DDIM * 2 + (size_t)KCB * DDIM * 2;
    float* sb1 = (float*)(ws + soff);
    int*   si1 = (int*)(ws + soff + (size_t)NSPLIT * N_TOT * 4);
    float* sb2 = (float*)(ws + soff + (size_t)NSPLIT * N_TOT * 8);
    size_t need = soff + (size_t)NSPLIT * N_TOT * 12;

    hipMemsetAsync(loss_acc, 0, 4, stream);
    if (ws_size >= need) {
        convert_x_kernel<<<(N_TOT * DDIM) / (256 * 8), 256, 0, stream>>>(x, xh);
        convert_cb_kernel<<<KCB / 4, 256, 0, stream>>>(cb, cbh, cnorm);
        dim3 grid(N_TOT / BN, NSPLIT);
        gemm_argmin_kernel<<<grid, 256, 0, stream>>>(xh, cbh, cnorm, sb1, si1, sb2);
        merge_kernel<<<N_TOT / 256, 256, 0, stream>>>(sb1, si1, sb2, indices, flags);
        repair_kernel<<<256, 256, 0, stream>>>(x, cb, cnorm, flags, indices);
    } else {
        cnorm_kernel<<<KCB / 4, 256, 0, stream>>>(cb, cnorm);
        argmin_fp32_kernel<<<N_TOT / FBN, 256, 0, stream>>>(x, cb, cnorm, indices);
    }
    output_kernel<<<((size_t)N_TOT * DDIM) / (256 * 16), 256, 0, stream>>>(
        x, cb, indices, out, loss_acc);
    finalize_kernel<<<1, 1, 0, stream>>>(loss_acc, out + (size_t)N_TOT * DDIM);
}

// Round 3
// 1434.578 us; speedup vs baseline: 3.2227x; 2.5950x over previous
//
#include <hip/hip_runtime.h>
#include <stdint.h>

#define N_TOT 32768
#define DDIM  512
#define KCB   8192
#define NSPLIT 4
#define COLS_SPLIT (KCB / NSPLIT)   // 2048
#define BN 128
#define BC 128
#define BKD 64                      // d-chunk depth in halfs
#define NTILES (COLS_SPLIT / BC)    // 16
#define MARGIN 0.15f
#define RPARTS 8
#define RROWS  (KCB / RPARTS)       // 1024
#define RGRID  2048                 // 256 row-slots x 8 parts, grid-stride beyond

typedef _Float16 half8 __attribute__((ext_vector_type(8)));
typedef float    floatx4 __attribute__((ext_vector_type(4)));

// ---------------- async global->LDS 16B ----------------
typedef const __attribute__((address_space(1))) unsigned int* gas_ptr;
typedef __attribute__((address_space(3))) unsigned int* las_ptr;
__device__ __forceinline__ void gld_lds16(void* l, const void* g) {
    __builtin_amdgcn_global_load_lds((gas_ptr)g, (las_ptr)l, 16, 0, 0);
}

// ---------------- convert x to fp16 ----------------
__global__ __launch_bounds__(256) void convert_x_kernel(
    const float* __restrict__ x, _Float16* __restrict__ xh) {
    size_t i = ((size_t)blockIdx.x * 256 + threadIdx.x) * 8;
    float4 v0 = *(const float4*)(x + i);
    float4 v1 = *(const float4*)(x + i + 4);
    half8 h;
    h[0] = (_Float16)v0.x; h[1] = (_Float16)v0.y; h[2] = (_Float16)v0.z; h[3] = (_Float16)v0.w;
    h[4] = (_Float16)v1.x; h[5] = (_Float16)v1.y; h[6] = (_Float16)v1.z; h[7] = (_Float16)v1.w;
    *(half8*)(xh + i) = h;
}

// ---------------- convert codebook to fp16 + fp32 norms (one wave/row) ----------------
__global__ __launch_bounds__(256) void convert_cb_kernel(
    const float* __restrict__ cb, _Float16* __restrict__ cbh, float* __restrict__ cnorm) {
    int row = blockIdx.x * 4 + (threadIdx.x >> 6);
    int lane = threadIdx.x & 63;
    const float* src = cb + (size_t)row * DDIM + lane * 8;
    float4 v0 = *(const float4*)src;
    float4 v1 = *(const float4*)(src + 4);
    half8 h;
    h[0] = (_Float16)v0.x; h[1] = (_Float16)v0.y; h[2] = (_Float16)v0.z; h[3] = (_Float16)v0.w;
    h[4] = (_Float16)v1.x; h[5] = (_Float16)v1.y; h[6] = (_Float16)v1.z; h[7] = (_Float16)v1.w;
    *(half8*)(cbh + (size_t)row * DDIM + lane * 8) = h;
    float s = v0.x*v0.x + v0.y*v0.y + v0.z*v0.z + v0.w*v0.w
            + v1.x*v1.x + v1.y*v1.y + v1.z*v1.z + v1.w*v1.w;
#pragma unroll
    for (int off = 32; off > 0; off >>= 1) s += __shfl_down(s, off, 64);
    if (lane == 0) cnorm[row] = s;
}

// ---------------- fused fp16 MFMA GEMM + per-row top-2 argmin (K-split) ----------------
__global__ __launch_bounds__(256, 2) void gemm_argmin_kernel(
    const _Float16* __restrict__ xh, const _Float16* __restrict__ cbh,
    const float* __restrict__ cnorm,
    float* __restrict__ sb1, int* __restrict__ si1, float* __restrict__ sb2) {

    __shared__ __align__(16) _Float16 smem[16384];  // As[128][64] + Bs[128][64], chunk-swizzled
    _Float16* As = smem;
    _Float16* Bs = smem + 8192;

    const int tid = threadIdx.x;
    const int wave = tid >> 6;
    const int lane = tid & 63;
    const int rowHalf = wave >> 1;
    const int colHalf = wave & 1;
    const int l15 = lane & 15;
    const int quad = lane >> 4;

    const int row0 = blockIdx.x * BN;
    const int colBase = blockIdx.y * COLS_SPLIT;

    float b1[16], b2[16];
    int   i1[16];
#pragma unroll
    for (int s = 0; s < 16; ++s) { b1[s] = 3.402823466e38f; b2[s] = 3.402823466e38f; i1[s] = 0; }

    for (int tile = 0; tile < NTILES; ++tile) {
        const int col0 = colBase + tile * BC;
        floatx4 acc[4][4];
#pragma unroll
        for (int i = 0; i < 4; ++i)
#pragma unroll
            for (int j = 0; j < 4; ++j)
                acc[i][j] = (floatx4){0.f, 0.f, 0.f, 0.f};

        for (int d0 = 0; d0 < DDIM; d0 += BKD) {
            __syncthreads();   // previous chunk's LDS reads done before overwrite
#pragma unroll
            for (int r = 0; r < 4; ++r) {
                int c = wave * 256 + r * 64 + lane;
                int ar = c >> 3;
                int q  = (c & 7) ^ (ar & 7);      // XOR swizzle: conflict-free frag reads
                gld_lds16(As + (wave * 256 + r * 64) * 8,
                          xh + (((size_t)(row0 + ar)) << 9) + d0 + q * 8);
            }
#pragma unroll
            for (int r = 0; r < 4; ++r) {
                int c = wave * 256 + r * 64 + lane;
                int br = c >> 3;
                int q  = (c & 7) ^ (br & 7);
                gld_lds16(Bs + (wave * 256 + r * 64) * 8,
                          cbh + (((size_t)(col0 + br)) << 9) + d0 + q * 8);
            }
            __syncthreads();   // loads visible
#pragma unroll
            for (int kh = 0; kh < 2; ++kh) {
                half8 af[4], bf[4];
#pragma unroll
                for (int i = 0; i < 4; ++i) {
                    int rr = rowHalf * 64 + i * 16 + l15;
                    int qs = (kh * 4 + quad) ^ (rr & 7);
                    af[i] = *(const half8*)(As + rr * 64 + qs * 8);
                }
#pragma unroll
                for (int j = 0; j < 4; ++j) {
                    int cc = colHalf * 64 + j * 16 + l15;
                    int qs = (kh * 4 + quad) ^ (cc & 7);
                    bf[j] = *(const half8*)(Bs + cc * 64 + qs * 8);
                }
#pragma unroll
                for (int i = 0; i < 4; ++i)
#pragma unroll
                    for (int j = 0; j < 4; ++j)
                        acc[i][j] = __builtin_amdgcn_mfma_f32_16x16x32_f16(
                            af[i], bf[j], acc[i][j], 0, 0, 0);
            }
        }
        // epilogue: fold scores into per-lane top-2
#pragma unroll
        for (int j = 0; j < 4; ++j) {
            int col = col0 + colHalf * 64 + j * 16 + l15;
            float cn = cnorm[col];
#pragma unroll
            for (int i = 0; i < 4; ++i) {
#pragma unroll
                for (int r = 0; r < 4; ++r) {
                    float s = fmaf(-2.0f, acc[i][j][r], cn);
                    int slot = i * 4 + r;
                    if (s < b1[slot]) { b2[slot] = b1[slot]; b1[slot] = s; i1[slot] = col; }
                    else if (s < b2[slot]) b2[slot] = s;
                }
            }
        }
    }

    // butterfly merge across the 16 col-lanes sharing each row
#pragma unroll
    for (int m = 1; m < 16; m <<= 1) {
#pragma unroll
        for (int s = 0; s < 16; ++s) {
            float ob1 = __shfl_xor(b1[s], m, 64);
            float ob2 = __shfl_xor(b2[s], m, 64);
            int   oi1 = __shfl_xor(i1[s], m, 64);
            if (ob1 < b1[s] || (ob1 == b1[s] && oi1 < i1[s])) {
                b2[s] = fminf(b1[s], ob2);
                b1[s] = ob1; i1[s] = oi1;
            } else {
                b2[s] = fminf(b2[s], ob1);
            }
        }
    }

    __syncthreads();   // done with As/Bs; reuse smem for cross-wave merge
    float* mb1 = (float*)smem;           // [2 colHalf][128 rows]
    float* mb2 = mb1 + 256;
    int*   mi1 = (int*)(mb2 + 256);
    if (l15 == 0) {
#pragma unroll
        for (int s = 0; s < 16; ++s) {
            int row = rowHalf * 64 + (s >> 2) * 16 + quad * 4 + (s & 3);
            mb1[colHalf * 128 + row] = b1[s];
            mb2[colHalf * 128 + row] = b2[s];
            mi1[colHalf * 128 + row] = i1[s];
        }
    }
    __syncthreads();
    if (tid < 128) {
        float a1 = mb1[tid], a2 = mb2[tid]; int ai = mi1[tid];
        float c1 = mb1[128 + tid], c2 = mb2[128 + tid]; int ci = mi1[128 + tid];
        float r1, r2; int ri;
        if (c1 < a1 || (c1 == a1 && ci < ai)) { r1 = c1; ri = ci; r2 = fminf(a1, c2); }
        else { r1 = a1; ri = ai; r2 = fminf(a2, c1); }
        size_t o = (size_t)blockIdx.y * N_TOT + row0 + tid;
        sb1[o] = r1; si1[o] = ri; sb2[o] = r2;
    }
}

// ---------------- merge K-splits, emit index + compact flagged-row list ----------------
__global__ __launch_bounds__(256) void merge_kernel(
    const float* __restrict__ sb1, const int* __restrict__ si1, const float* __restrict__ sb2,
    int* __restrict__ indices, int* __restrict__ flags,
    int* __restrict__ list, int* __restrict__ count,
    unsigned long long* __restrict__ result) {
    int n = blockIdx.x * 256 + threadIdx.x;
    float b1 = sb1[n]; int i1 = si1[n]; float b2 = sb2[n];
#pragma unroll
    for (int s = 1; s < NSPLIT; ++s) {
        float ob1 = sb1[(size_t)s * N_TOT + n];
        int   oi1 = si1[(size_t)s * N_TOT + n];
        float ob2 = sb2[(size_t)s * N_TOT + n];
        if (ob1 < b1 || (ob1 == b1 && oi1 < i1)) { b2 = fminf(b1, ob2); b1 = ob1; i1 = oi1; }
        else b2 = fminf(b2, ob1);
    }
    indices[n] = i1;
    result[n] = 0xFFFFFFFFFFFFFFFFull;
    int f = (b2 - b1 < MARGIN) ? 1 : 0;
    flags[n] = f;
    if (f) { int pos = atomicAdd(count, 1); list[pos] = n; }
}

// ---------------- exact fp32 rescan for flagged rows (8 blocks per row) ----------------
__global__ __launch_bounds__(256) void repair2_kernel(
    const float* __restrict__ x, const float* __restrict__ cb,
    const float* __restrict__ cnorm, const int* __restrict__ list,
    const int* __restrict__ count, unsigned long long* __restrict__ result) {
    __shared__ float xrow[512];
    __shared__ unsigned long long red[256];
    const int tid = threadIdx.x;
    const int nslots = RGRID / RPARTS;
    const int slot0 = blockIdx.x / RPARTS;
    const int part = blockIdx.x % RPARTS;
    const int cnt = *count;
    for (int slot = slot0; slot < cnt; slot += nslots) {
        int n = list[slot];
        __syncthreads();   // previous iter's xrow/red reads done
        for (int t = tid; t < 512; t += 256) xrow[t] = x[(size_t)n * 512 + t];
        __syncthreads();
        float best = 3.402823466e38f; int bidx = KCB;
        for (int kk = tid; kk < RROWS; kk += 256) {
            int k = part * RROWS + kk;
            const float* crow = cb + (size_t)k * 512;
            float d0 = 0.f, d1 = 0.f, d2 = 0.f, d3 = 0.f;
            for (int t = 0; t < 512; t += 16) {
                float4 c0 = *(const float4*)(crow + t);
                float4 c1 = *(const float4*)(crow + t + 4);
                float4 c2 = *(const float4*)(crow + t + 8);
                float4 c3 = *(const float4*)(crow + t + 12);
                d0 = fmaf(c0.x, xrow[t+0], d0);  d0 = fmaf(c0.y, xrow[t+1], d0);
                d0 = fmaf(c0.z, xrow[t+2], d0);  d0 = fmaf(c0.w, xrow[t+3], d0);
                d1 = fmaf(c1.x, xrow[t+4], d1);  d1 = fmaf(c1.y, xrow[t+5], d1);
                d1 = fmaf(c1.z, xrow[t+6], d1);  d1 = fmaf(c1.w, xrow[t+7], d1);
                d2 = fmaf(c2.x, xrow[t+8], d2);  d2 = fmaf(c2.y, xrow[t+9], d2);
                d2 = fmaf(c2.z, xrow[t+10], d2); d2 = fmaf(c2.w, xrow[t+11], d2);
                d3 = fmaf(c3.x, xrow[t+12], d3); d3 = fmaf(c3.y, xrow[t+13], d3);
                d3 = fmaf(c3.z, xrow[t+14], d3); d3 = fmaf(c3.w, xrow[t+15], d3);
            }
            float s = cnorm[k] - 2.f * ((d0 + d1) + (d2 + d3));
            if (s < best) { best = s; bidx = k; }   // strided k increases per thread: first-min kept
        }
        // pack (ordered score bits, index) so u64 min == (min score, then min index)
        unsigned int sb = __float_as_uint(best);
        sb = (sb & 0x80000000u) ? ~sb : (sb | 0x80000000u);
        red[tid] = ((unsigned long long)sb << 32) | (unsigned int)bidx;
        __syncthreads();
        for (int s = 128; s > 0; s >>= 1) {
            if (tid < s) { if (red[tid + s] < red[tid]) red[tid] = red[tid + s]; }
            __syncthreads();
        }
        if (tid == 0) atomicMin(&result[n], red[0]);
    }
}

// ---------------- apply repaired indices ----------------
__global__ __launch_bounds__(256) void fixup_kernel(
    const int* __restrict__ flags, const unsigned long long* __restrict__ result,
    int* __restrict__ indices) {
    int n = blockIdx.x * 256 + threadIdx.x;
    if (flags[n]) indices[n] = (int)(result[n] & 0xFFFFFFFFu);
}

// ---------------- fallback fp32 argmin (used only if ws too small) ----------------
__global__ void cnorm_kernel(const float* __restrict__ cb, float* __restrict__ cnorm) {
    int wave = (blockIdx.x * blockDim.x + threadIdx.x) >> 6;
    int lane = threadIdx.x & 63;
    if (wave >= KCB) return;
    const float* row = cb + (size_t)wave * DDIM;
    float s = 0.f;
#pragma unroll
    for (int j = 0; j < DDIM / 64; ++j) { float v = row[lane + 64 * j]; s += v * v; }
#pragma unroll
    for (int off = 32; off > 0; off >>= 1) s += __shfl_down(s, off, 64);
    if (lane == 0) cnorm[wave] = s;
}

#define FBN 64
#define FBD 32
#define FLDA (FBN + 4)
__global__ __launch_bounds__(256) void argmin_fp32_kernel(
    const float* __restrict__ x, const float* __restrict__ cb,
    const float* __restrict__ cnorm, int* __restrict__ indices) {
    __shared__ float As[FBD][FLDA];
    __shared__ float Bs[FBD][FLDA];
    __shared__ float redv[FBN][16];
    __shared__ int   redi[FBN][16];
    const int tid = threadIdx.x;
    const int tx = tid & 15, ty = tid >> 4;
    const int row0 = blockIdx.x * FBN;
    float best[4]; int bidx[4];
#pragma unroll
    for (int i = 0; i < 4; ++i) { best[i] = 3.402823466e+38f; bidx[i] = KCB; }
    for (int k0 = 0; k0 < KCB; k0 += 64) {
        float acc[4][4] = {};
        for (int d0 = 0; d0 < DDIM; d0 += FBD) {
#pragma unroll
            for (int t = 0; t < 2; ++t) {
                int q = tid + t * 256, rr = q >> 3, dq = q & 7;
                float4 v = *(const float4*)(x + (size_t)(row0 + rr) * DDIM + d0 + dq * 4);
                As[dq*4+0][rr] = v.x; As[dq*4+1][rr] = v.y; As[dq*4+2][rr] = v.z; As[dq*4+3][rr] = v.w;
                float4 w = *(const float4*)(cb + (size_t)(k0 + rr) * DDIM + d0 + dq * 4);
                Bs[dq*4+0][rr] = w.x; Bs[dq*4+1][rr] = w.y; Bs[dq*4+2][rr] = w.z; Bs[dq*4+3][rr] = w.w;
            }
            __syncthreads();
#pragma unroll
            for (int d = 0; d < FBD; ++d) {
                float4 av = *(const float4*)&As[d][ty * 4];
                float4 bv = *(const float4*)&Bs[d][tx * 4];
                float a[4] = {av.x, av.y, av.z, av.w}, b[4] = {bv.x, bv.y, bv.z, bv.w};
#pragma unroll
                for (int i = 0; i < 4; ++i)
#pragma unroll
                    for (int j = 0; j < 4; ++j) acc[i][j] += a[i] * b[j];
            }
            __syncthreads();
        }
#pragma unroll
        for (int j = 0; j < 4; ++j) {
            int k = k0 + tx * 4 + j;
            float cn = cnorm[k];
#pragma unroll
            for (int i = 0; i < 4; ++i) {
                float s = cn - 2.0f * acc[i][j];
                if (s < best[i] || (s == best[i] && k < bidx[i])) { best[i] = s; bidx[i] = k; }
            }
        }
    }
#pragma unroll
    for (int i = 0; i < 4; ++i) { redv[ty*4+i][tx] = best[i]; redi[ty*4+i][tx] = bidx[i]; }
    __syncthreads();
    if (tid < FBN) {
        float bv = redv[tid][0]; int bi = redi[tid][0];
#pragma unroll
        for (int t = 1; t < 16; ++t) {
            float v = redv[tid][t]; int ii = redi[tid][t];
            if (v < bv || (v == bv && ii < bi)) { bv = v; bi = ii; }
        }
        indices[row0 + tid] = bi;
    }
}

// ---------------- gather + straight-through output + loss ----------------
__global__ __launch_bounds__(256) void output_kernel(
    const float* __restrict__ x, const float* __restrict__ cb,
    const int* __restrict__ indices, float* __restrict__ out,
    float* __restrict__ loss_acc) {
    size_t base = ((size_t)blockIdx.x * blockDim.x + threadIdx.x) * 16;
    int n = (int)(base >> 9);
    int d = (int)(base & 511);
    int idx = indices[n];
    const float* cr = cb + (size_t)idx * DDIM + d;
    const float* xr = x + base;
    float* orow = out + base;
    float lsum = 0.f;
#pragma unroll
    for (int t = 0; t < 4; ++t) {
        float4 q  = *(const float4*)(cr + t * 4);
        float4 xv = *(const float4*)(xr + t * 4);
        float dx0 = q.x - xv.x, dx1 = q.y - xv.y, dx2 = q.z - xv.z, dx3 = q.w - xv.w;
        float4 o;
        o.x = xv.x + dx0; o.y = xv.y + dx1; o.z = xv.z + dx2; o.w = xv.w + dx3;
        *(float4*)(orow + t * 4) = o;
        lsum += dx0*dx0 + dx1*dx1 + dx2*dx2 + dx3*dx3;
    }
#pragma unroll
    for (int off = 32; off > 0; off >>= 1) lsum += __shfl_down(lsum, off, 64);
    __shared__ float wsum[4];
    int lane = threadIdx.x & 63, wv = threadIdx.x >> 6;
    if (lane == 0) wsum[wv] = lsum;
    __syncthreads();
    if (threadIdx.x == 0) atomicAdd(loss_acc, wsum[0] + wsum[1] + wsum[2] + wsum[3]);
}

__global__ void finalize_kernel(const float* __restrict__ loss_acc, float* __restrict__ out_loss) {
    *out_loss = (*loss_acc) * (0.25f / (float)((size_t)N_TOT * DDIM));
}

extern "C" void kernel_launch(void* const* d_in, const int* in_sizes, int n_in,
                              void* d_out, int out_size, void* d_ws, size_t ws_size,
                              hipStream_t stream) {
    const float* x  = (const float*)d_in[0];
    const float* cb = (const float*)d_in[1];
    float* out = (float*)d_out;

    char* ws = (char*)d_ws;
    float* loss_acc = (float*)ws;                                 // 4 B
    int*   count    = (int*)(ws + 8);                             // 4 B
    int*   indices  = (int*)(ws + 256);                           // 128 KiB
    int*   flags    = (int*)(ws + 256 + 131072);                  // 128 KiB
    float* cnorm    = (float*)(ws + 256 + 2 * 131072);            // 32 KiB
    int*   list     = (int*)(ws + 256 + 2 * 131072 + 32768);      // 128 KiB
    unsigned long long* result =
        (unsigned long long*)(ws + 256 + 3 * 131072 + 32768);     // 256 KiB
    size_t off = 256 + 3 * 131072 + 32768 + 262144;               // ~0.69 MiB, 256-aligned
    _Float16* xh  = (_Float16*)(ws + off);                        // 32 MiB
    _Float16* cbh = (_Float16*)(ws + off + (size_t)N_TOT * DDIM * 2);  // 8 MiB
    size_t soff = off + (size_t)N_TOT * DDIM * 2 + (size_t)KCB * DDIM * 2;
    float* sb1 = (float*)(ws + soff);
    int*   si1 = (int*)(ws + soff + (size_t)NSPLIT * N_TOT * 4);
    float* sb2 = (float*)(ws + soff + (size_t)NSPLIT * N_TOT * 8);
    size_t need = soff + (size_t)NSPLIT * N_TOT * 12;

    hipMemsetAsync(ws, 0, 16, stream);   // loss_acc + count
    if (ws_size >= need) {
        convert_x_kernel<<<(N_TOT * DDIM) / (256 * 8), 256, 0, stream>>>(x, xh);
        convert_cb_kernel<<<KCB / 4, 256, 0, stream>>>(cb, cbh, cnorm);
        dim3 grid(N_TOT / BN, NSPLIT);
        gemm_argmin_kernel<<<grid, 256, 0, stream>>>(xh, cbh, cnorm, sb1, si1, sb2);
        merge_kernel<<<N_TOT / 256, 256, 0, stream>>>(sb1, si1, sb2, indices, flags,
                                                      list, count, result);
        repair2_kernel<<<RGRID, 256, 0, stream>>>(x, cb, cnorm, list, count, result);
        fixup_kernel<<<N_TOT / 256, 256, 0, stream>>>(flags, result, indices);
    } else {
        cnorm_kernel<<<KCB / 4, 256, 0, stream>>>(cb, cnorm);
        argmin_fp32_kernel<<<N_TOT / FBN, 256, 0, stream>>>(x, cb, cnorm, indices);
    }
    output_kernel<<<((size_t)N_TOT * DDIM) / (256 * 16), 256, 0, stream>>>(
        x, cb, indices, out, loss_acc);
    finalize_kernel<<<1, 1, 0, stream>>>(loss_acc, out + (size_t)N_TOT * DDIM);
}